// Round 18
// baseline (2002.568 us; speedup 1.0000x reference)
//
#include <hip/hip_runtime.h>
#include <cstdint>

#define BB 2
#define NN 1024
#define FF 2048
#define CC 80
#define C2 160
#define NB_ 15
#define ROWS_X (BB*FF)   /* 4096 */
#define ROWS_Y (BB*NN)   /* 2048 */
#define WTP 168          /* padded LDS row stride (fp16 elems) */

typedef __attribute__((ext_vector_type(8))) _Float16 half8;
typedef __attribute__((ext_vector_type(4))) _Float16 half4;
typedef __attribute__((ext_vector_type(4))) float f32x4;

// Soft barrier: sync waves + drain own LDS writes; no vmcnt drain.
__device__ __forceinline__ void softbar() {
  __builtin_amdgcn_sched_barrier(0);
  asm volatile("s_waitcnt lgkmcnt(0)" ::: "memory");
  __builtin_amdgcn_s_barrier();
  __builtin_amdgcn_sched_barrier(0);
}

// ---------------- conv1: v = in@W0 + (L@in)@W1 + b, + v-stats (128 slots, float4-pair) ----------
__global__ __launch_bounds__(256) void k_conv1(
    const float* __restrict__ inp, const float* __restrict__ L,
    const float* __restrict__ W0, const float* __restrict__ W1,
    const float* __restrict__ bias, float* __restrict__ v,
    float4* __restrict__ vstat)
{
  int bx = blockIdx.x;            // 128 = 2 batches x 64 row-blocks
  int b = bx >> 6, rb = bx & 63;
  int row0 = rb * 16;
  __shared__ float red[256][3];
  __shared__ float lx[16][3];
  __shared__ float st[16][2][CC];
  int t = threadIdx.x;
  int rloc = t >> 4, sl = t & 15;
  const float* Lrow = L + ((size_t)b*NN + row0 + rloc) * NN;
  const float* ipb  = inp + (size_t)b*NN*3;
  float a0=0.f,a1=0.f,a2=0.f;
  for (int m = sl; m < NN; m += 16) {
    float lv = Lrow[m];
    a0 = fmaf(lv, ipb[m*3+0], a0);
    a1 = fmaf(lv, ipb[m*3+1], a1);
    a2 = fmaf(lv, ipb[m*3+2], a2);
  }
  red[t][0]=a0; red[t][1]=a1; red[t][2]=a2;
  __syncthreads();
  if (t < 48) {
    int row = t/3, ci = t%3;
    float s=0.f;
    for (int s2=0; s2<16; ++s2) s += red[row*16+s2][ci];
    lx[row][ci]=s;
  }
  __syncthreads();
  for (int o = t; o < 16*CC; o += 256) {
    int row = o/CC, c = o%CC;
    const float* ir = inp + ((size_t)b*NN + row0 + row)*3;
    float val = bias[c];
    #pragma unroll
    for (int ci=0; ci<3; ++ci)
      val += ir[ci]*W0[ci*CC+c] + lx[row][ci]*W1[ci*CC+c];
    v[((size_t)b*NN + row0 + row)*CC + c] = val;
    st[row][0][c] = val;
    st[row][1][c] = val*val;
  }
  __syncthreads();
  if (t < 40) {
    float s0=0.f,q0=0.f,s1=0.f,q1=0.f;
    for (int row=0; row<16; ++row){
      s0+=st[row][0][2*t];   q0+=st[row][1][2*t];
      s1+=st[row][0][2*t+1]; q1+=st[row][1][2*t+1];
    }
    vstat[(size_t)bx*40 + t] = make_float4(s0,q0,s1,q1);
  }
}

// ---------------- MFMA Dirac (chunk=128, 4 blocks/CU): y = A@x + stats ----------
// LDS xT[2][2][32][136] = 34.8 KB -> 4 blocks/CU = 16 waves/CU (was 71 KB ->
// 2 blocks/CU; rounds 14-16 missed that LDS, not grid, capped occupancy).
// cb_/stats live in the xT footprint post-loop (aliased after final softbar).
// waves_per_eu(4,4): 128-VGPR budget; demand ~110 (staging 5 float4, a-ring 4).
// CVT=true (it=0): A read f32, cvt in-register, fp16 copy stored to Aout.
template<bool CVT>
__global__ __launch_bounds__(256) __attribute__((amdgpu_waves_per_eu(4,4)))
void k_dirac_mfma(
    const void* __restrict__ Ain, _Float16* __restrict__ Aout,
    const float* __restrict__ x,
    float* __restrict__ y, float4* __restrict__ stat, int M, int K)
{
  constexpr int CH = 128;                  // k-chunk per half
  int b = blockIdx.y;
  x += (size_t)b*(size_t)K*20; y += (size_t)b*(size_t)M*20;
  const _Float16* Ah = (const _Float16*)Ain + (size_t)b*M*K;
  const float*    Af = (const float*)Ain    + (size_t)b*M*K;
  _Float16* Ao = CVT ? (Aout + (size_t)b*M*K) : nullptr;
  __shared__ _Float16 xT[2][2][32][136];
  int t = threadIdx.x, lane = t & 63, w = t >> 6;
  int rw = w & 1, kh = w >> 1;
  int row0 = blockIdx.x*32 + rw*16;
  int cl = lane & 15, cg = lane >> 4;
  int KH = K >> 1;
  int hh_t = t >> 7, tt = t & 127;         // staging: half, k-row within chunk
  f32x4 acc0 = {0.f,0.f,0.f,0.f}, acc1 = {0.f,0.f,0.f,0.f};
  const float4* xv = (const float4*)x;     // x row k = 5 float4s
  int nchunk = KH >> 7;
  size_t aoff = (size_t)(row0 + cl)*K + (size_t)kh*KH + cg*8;

  // zero pad cols 20..31 of both buffers & halves (never re-touched)
  for (int i = t; i < 2*2*12*136; i += 256) {
    int bb = i / (2*12*136);
    int rem = i - bb*(2*12*136);
    int hh = rem / (12*136);
    int r2 = rem - hh*(12*136);
    xT[bb][hh][20 + r2/136][r2 % 136] = (_Float16)0.f;
  }
  { // stage chunk 0 (each thread: one k-row of one half)
    float4 s[5];
    size_t kr = (size_t)hh_t*KH + tt;
    #pragma unroll
    for (int i=0;i<5;++i) s[i] = xv[kr*5+i];
    #pragma unroll
    for (int i=0;i<5;++i){
      xT[0][hh_t][4*i+0][tt]=(_Float16)s[i].x; xT[0][hh_t][4*i+1][tt]=(_Float16)s[i].y;
      xT[0][hh_t][4*i+2][tt]=(_Float16)s[i].z; xT[0][hh_t][4*i+3][tt]=(_Float16)s[i].w;
    }
  }
  half8 a_cur[4];
  if constexpr (!CVT) {
    #pragma unroll
    for (int ks=0;ks<4;++ks) a_cur[ks] = *(const half8*)(Ah + aoff + ks*32);
  }
  __syncthreads();

  for (int c=0; c<nchunk; ++c) {
    int cur = c & 1;
    bool more = (c+1 < nchunk);
    float4 s[5];
    half8 a_nxt[4];
    if (more) {                            // issue next-chunk x loads early
      size_t kr = (size_t)hh_t*KH + (size_t)(c+1)*CH + tt;
      #pragma unroll
      for (int i=0;i<5;++i) s[i] = xv[kr*5+i];
      if constexpr (!CVT) {
        const _Float16* An = Ah + aoff + (size_t)(c+1)*CH;
        #pragma unroll
        for (int ks=0;ks<4;++ks) a_nxt[ks] = *(const half8*)(An + ks*32);
      }
    }
    if constexpr (CVT) {                   // load f32 A this chunk, cvt, store
      size_t ao = aoff + (size_t)c*CH;
      #pragma unroll
      for (int ks=0;ks<4;++ks) {
        float4 f0 = *(const float4*)(Af + ao + ks*32);
        float4 f1 = *(const float4*)(Af + ao + ks*32 + 4);
        half8 a;
        a[0]=(_Float16)f0.x; a[1]=(_Float16)f0.y; a[2]=(_Float16)f0.z; a[3]=(_Float16)f0.w;
        a[4]=(_Float16)f1.x; a[5]=(_Float16)f1.y; a[6]=(_Float16)f1.z; a[7]=(_Float16)f1.w;
        a_cur[ks] = a;
        *(half8*)(Ao + ao + ks*32) = a;
      }
    }
    #pragma unroll
    for (int ks=0;ks<4;++ks) {
      half8 b0 = *(const half8*)(&xT[cur][kh][cl     ][ks*32 + cg*8]);
      half8 b1 = *(const half8*)(&xT[cur][kh][16 + cl][ks*32 + cg*8]);
      acc0 = __builtin_amdgcn_mfma_f32_16x16x32_f16(a_cur[ks], b0, acc0, 0,0,0);
      acc1 = __builtin_amdgcn_mfma_f32_16x16x32_f16(a_cur[ks], b1, acc1, 0,0,0);
    }
    if (more) {                            // publish next buffer, rotate A
      #pragma unroll
      for (int i=0;i<5;++i){
        xT[cur^1][hh_t][4*i+0][tt]=(_Float16)s[i].x; xT[cur^1][hh_t][4*i+1][tt]=(_Float16)s[i].y;
        xT[cur^1][hh_t][4*i+2][tt]=(_Float16)s[i].z; xT[cur^1][hh_t][4*i+3][tt]=(_Float16)s[i].w;
      }
      if constexpr (!CVT) {
        #pragma unroll
        for (int ks=0;ks<4;++ks) a_cur[ks] = a_nxt[ks];
      }
    }
    softbar();                             // sync waves WITHOUT vmcnt drain
  }

  // post-loop scratch aliased into xT (all xT reads complete at final softbar)
  float* scr = (float*)&xT[0][0][0][0];
  // cb: [2 rw][8 j][64 lane] floats at 0; stS at 1024; stQ at 1184
  float* pS = scr + 1024;
  float* pQ = scr + 1184;

  // combine k-halves: waves kh=1 publish, kh=0 accumulate
  if (kh == 1) {
    #pragma unroll
    for (int j=0;j<4;++j){
      scr[(rw*8+j  )*64 + lane]=acc0[j];
      scr[(rw*8+4+j)*64 + lane]=acc1[j];
    }
  }
  __syncthreads();
  if (kh == 0) {
    #pragma unroll
    for (int j=0;j<4;++j){
      acc0[j]+=scr[(rw*8+j  )*64 + lane];
      acc1[j]+=scr[(rw*8+4+j)*64 + lane];
    }
    #pragma unroll
    for (int j=0;j<4;++j) {
      float v = acc0[j];
      y[(size_t)(row0 + 4*cg + j)*20 + cl] = v;
      float s = v, sq = v*v;
      s  += __shfl_xor(s,16);  s  += __shfl_xor(s,32);
      sq += __shfl_xor(sq,16); sq += __shfl_xor(sq,32);
      if (cg==0) { pS[rw*CC + j*20+cl]=s; pQ[rw*CC + j*20+cl]=sq; }
    }
    #pragma unroll
    for (int j=0;j<4;++j) {
      float v = acc1[j];                   // cols>=4 exact 0 (zero pad)
      if (cl < 4) y[(size_t)(row0 + 4*cg + j)*20 + 16 + cl] = v;
      float s = v, sq = v*v;
      s  += __shfl_xor(s,16);  s  += __shfl_xor(s,32);
      sq += __shfl_xor(sq,16); sq += __shfl_xor(sq,32);
      if (cg==0 && cl<4) { pS[rw*CC + j*20+16+cl]=s; pQ[rw*CC + j*20+16+cl]=sq; }
    }
  }
  __syncthreads();
  int slot = blockIdx.y*gridDim.x + blockIdx.x;
  if (t < 40) {
    float4 o;
    o.x = pS[2*t]      + pS[CC+2*t];
    o.y = pQ[2*t]      + pQ[CC+2*t];
    o.z = pS[2*t+1]    + pS[CC+2*t+1];
    o.w = pQ[2*t+1]    + pQ[CC+2*t+1];
    stat[(size_t)slot*40 + t] = o;
  }
}

// ---------------- f32 FMA Dirac fallback (ws too small) ----------------
__global__ __launch_bounds__(256) __attribute__((amdgpu_waves_per_eu(2,2)))
void k_dirac_f32(
    const float* __restrict__ A, const float* __restrict__ x,
    float* __restrict__ y, float4* __restrict__ stat, int M, int K)
{
  const int DR = 4;
  int b = blockIdx.y;
  A += (size_t)b*M*K; x += (size_t)b*(size_t)K*20; y += (size_t)b*(size_t)M*20;
  __shared__ float xs[2][20][256];
  __shared__ float stS[4][CC], stQ[4][CC];
  int t = threadIdx.x, lane = t & 63, w = t >> 6;
  int row0 = blockIdx.x*(4*DR) + w*DR;
  float acc[DR][20];
  #pragma unroll
  for (int r=0;r<DR;++r)
    #pragma unroll
    for (int q=0;q<20;++q) acc[r][q]=0.f;
  const float4* xv = (const float4*)x;
  int nchunk = K >> 8;
  const float* Abase = A + (size_t)row0*K + (lane<<2);
  {
    float4 s0[5];
    #pragma unroll
    for (int i=0;i<5;++i) s0[i] = xv[(size_t)t*5 + i];
    #pragma unroll
    for (int i=0;i<5;++i) {
      xs[0][4*i+0][t]=s0[i].x; xs[0][4*i+1][t]=s0[i].y;
      xs[0][4*i+2][t]=s0[i].z; xs[0][4*i+3][t]=s0[i].w;
    }
  }
  float4 a[DR];
  #pragma unroll
  for (int r=0;r<DR;++r) a[r] = *(const float4*)(Abase + (size_t)r*K);
  __syncthreads();
  for (int c=0; c<nchunk; ++c) {
    int cur = c & 1;
    bool more = (c+1 < nchunk);
    float4 st[5];
    if (more) {
      size_t kb = (size_t)(c+1)*256 + t;
      #pragma unroll
      for (int i=0;i<5;++i) st[i] = xv[kb*5 + i];
    }
    float4 af[DR];
    #pragma unroll
    for (int r=0;r<DR;++r) af[r] = a[r];
    if (more) {
      const float* An = Abase + (size_t)(c+1)*256;
      #pragma unroll
      for (int r=0;r<DR;++r) a[r] = *(const float4*)(An + (size_t)r*K);
    }
    #pragma unroll
    for (int q=0;q<20;++q) {
      float4 xq = *(const float4*)(&xs[cur][q][lane<<2]);
      #pragma unroll
      for (int r=0;r<DR;++r) {
        acc[r][q] = fmaf(af[r].x, xq.x, acc[r][q]);
        acc[r][q] = fmaf(af[r].y, xq.y, acc[r][q]);
        acc[r][q] = fmaf(af[r].z, xq.z, acc[r][q]);
        acc[r][q] = fmaf(af[r].w, xq.w, acc[r][q]);
      }
    }
    if (more) {
      #pragma unroll
      for (int i=0;i<5;++i) {
        xs[cur^1][4*i+0][t]=st[i].x; xs[cur^1][4*i+1][t]=st[i].y;
        xs[cur^1][4*i+2][t]=st[i].z; xs[cur^1][4*i+3][t]=st[i].w;
      }
    }
    __syncthreads();
  }
  #pragma unroll
  for (int r=0;r<DR;++r) {
    #pragma unroll
    for (int q=0;q<20;++q) {
      float s = acc[r][q];
      s += __shfl_xor(s, 1);  s += __shfl_xor(s, 2);
      s += __shfl_xor(s, 4);  s += __shfl_xor(s, 8);
      s += __shfl_xor(s, 16); s += __shfl_xor(s, 32);
      acc[r][q]=s;
    }
    if (lane==0) {
      float4* yp = (float4*)(y + (size_t)(row0+r)*20);
      yp[0] = make_float4(acc[r][0],acc[r][1],acc[r][2],acc[r][3]);
      yp[1] = make_float4(acc[r][4],acc[r][5],acc[r][6],acc[r][7]);
      yp[2] = make_float4(acc[r][8],acc[r][9],acc[r][10],acc[r][11]);
      yp[3] = make_float4(acc[r][12],acc[r][13],acc[r][14],acc[r][15]);
      yp[4] = make_float4(acc[r][16],acc[r][17],acc[r][18],acc[r][19]);
    }
  }
  if (lane == 0) {
    #pragma unroll
    for (int r=0;r<DR;++r)
      #pragma unroll
      for (int q=0;q<20;++q) {
        float v0 = acc[r][q];
        stS[w][r*20+q] = v0;
        stQ[w][r*20+q] = v0*v0;
      }
  }
  __syncthreads();
  int slot = blockIdx.y*gridDim.x + blockIdx.x;
  if (t < 40) {
    float4 o;
    o.x = stS[0][2*t]+stS[1][2*t]+stS[2][2*t]+stS[3][2*t];
    o.y = stQ[0][2*t]+stQ[1][2*t]+stQ[2][2*t]+stQ[3][2*t];
    o.z = stS[0][2*t+1]+stS[1][2*t+1]+stS[2][2*t+1]+stS[3][2*t+1];
    o.w = stQ[0][2*t+1]+stQ[1][2*t+1]+stQ[2][2*t+1]+stQ[3][2*t+1];
    stat[(size_t)slot*40 + t] = o;
  }
}

// ---------------- MFMA fused BN(fold)+FC+ELU+residual + stats ----------------
__global__ __launch_bounds__(320) void k_fc(
    const float* __restrict__ p1, const float* __restrict__ p2,
    const float4* __restrict__ sp1, int ns1,
    const float4* __restrict__ sp2, int ns2,
    const float* __restrict__ g, const float* __restrict__ bb,
    const float* __restrict__ W, const float* __restrict__ cb,
    const float* add, float* out,
    float4* __restrict__ statout, int rows, float invrows)
{
  __shared__ _Float16 Wt[80*WTP];
  __shared__ _Float16 xh[16*WTP];
  __shared__ float ad[2][C2];
  __shared__ float bpl[CC];
  __shared__ float4 pst[2][2][40];
  __shared__ float stS[CC], stQ[CC];
  int t = threadIdx.x;
  int lane = t & 63, wv = t >> 6;          // wv = col-tile 0..4
  int cl = lane & 15, cg = lane >> 4;
  int r0 = blockIdx.x * 16;

  // phase 0: stats reduce (t<160)  ||  W transpose+fp16 convert (t>=160)
  if (t < 160) {
    int p = t % 40, s = (t/40) & 1, h = t/80;
    const float4* sp = s ? sp2 : sp1;
    int ns = s ? ns2 : ns1;
    int half = ns >> 1;
    const float4* base = sp + (size_t)(h*half)*40 + p;
    float4 acc = {0.f,0.f,0.f,0.f};
    int i=0;
    for (; i+8<=half; i+=8) {
      float4 v[8];
      #pragma unroll
      for (int j=0;j<8;++j) v[j] = base[(size_t)(i+j)*40];
      #pragma unroll
      for (int j=0;j<8;++j){ acc.x+=v[j].x; acc.y+=v[j].y; acc.z+=v[j].z; acc.w+=v[j].w; }
    }
    for (; i<half; ++i){
      float4 v = base[(size_t)i*40];
      acc.x+=v.x; acc.y+=v.y; acc.z+=v.z; acc.w+=v.w;
    }
    pst[h][s][p] = acc;
  } else {
    int t2 = t - 160;                      // 0..159; 20 float4 each = 3200 total
    #pragma unroll
    for (int i=0;i<20;++i) {
      int f4 = t2 + i*160;
      float4 w4 = ((const float4*)W)[f4];
      int c2 = f4/20, c = (f4%20)*4;
      Wt[(c+0)*WTP + c2] = (_Float16)w4.x;
      Wt[(c+1)*WTP + c2] = (_Float16)w4.y;
      Wt[(c+2)*WTP + c2] = (_Float16)w4.z;
      Wt[(c+3)*WTP + c2] = (_Float16)w4.w;
    }
  }
  __syncthreads();

  // phase 1: BN fold coeffs (t<160)  ||  all threads: B-frags from Wt -> regs
  half8 bfr[5];
  #pragma unroll
  for (int ks=0;ks<5;++ks)
    bfr[ks] = *(const half8*)(&Wt[(wv*16+cl)*WTP + ks*32 + cg*8]);
  if (t < C2) {
    int s = (t < CC) ? 0 : 1;
    int chl = (t < CC) ? t : t - CC;
    int p = chl >> 1, e = chl & 1;
    float4 a0 = pst[0][s][p], a1 = pst[1][s][p];
    float S = e ? (a0.z + a1.z) : (a0.x + a1.x);
    float Q = e ? (a0.w + a1.w) : (a0.y + a1.y);
    float mean = S*invrows;
    float var  = fmaf(-mean, mean, Q*invrows);
    float aa   = g[t]*rsqrtf(var + 1e-5f);
    ad[0][t]=aa; ad[1][t]= bb[t] - mean*aa;
  }
  __syncthreads();

  // phase 2: stage x-hat (16 rows, scaled by ad0, fp16)  ||  t<80: bpl
  #pragma unroll
  for (int i=0;i<2;++i) {
    int f4 = t + i*320;                    // 0..639
    if (f4 < 640) {
      int row = f4/40, cq = (f4%40)*4;     // cq in 0..156, never crosses 80
      const float* src = (cq < 80) ? (p1 + (size_t)(r0+row)*CC + cq)
                                   : (p2 + (size_t)(r0+row)*CC + cq - 80);
      float4 x4 = *(const float4*)src;
      half4 h4;
      h4[0]=(_Float16)(x4.x*ad[0][cq+0]); h4[1]=(_Float16)(x4.y*ad[0][cq+1]);
      h4[2]=(_Float16)(x4.z*ad[0][cq+2]); h4[3]=(_Float16)(x4.w*ad[0][cq+3]);
      *(half4*)(&xh[row*WTP + cq]) = h4;
    }
  }
  if (t < CC) {
    float s = cb[t];
    #pragma unroll
    for (int ks=0;ks<20;++ks) {
      half8 w8 = *(const half8*)(&Wt[t*WTP + ks*8]);
      #pragma unroll
      for (int j=0;j<8;++j) s = fmaf(ad[1][ks*8+j], (float)w8[j], s);
    }
    bpl[t]=s;
  }
  __syncthreads();

  // phase 3: A-frags, 5 MFMA, epilogue
  half8 afr[5];
  #pragma unroll
  for (int ks=0;ks<5;++ks)
    afr[ks] = *(const half8*)(&xh[cl*WTP + ks*32 + cg*8]);
  f32x4 acc = {0.f,0.f,0.f,0.f};
  #pragma unroll
  for (int ks=0;ks<5;++ks)
    acc = __builtin_amdgcn_mfma_f32_16x16x32_f16(afr[ks], bfr[ks], acc, 0,0,0);
  float ss=0.f, sq=0.f;
  int col = wv*16 + cl;
  #pragma unroll
  for (int j=0;j<4;++j) {
    int row = r0 + 4*cg + j;
    float val = acc[j] + bpl[col];
    val = val>0.f ? val : expm1f(val);
    val += add[(size_t)row*CC + col];
    out[(size_t)row*CC + col] = val;
    ss += val; sq = fmaf(val,val,sq);
  }
  ss += __shfl_xor(ss,16); ss += __shfl_xor(ss,32);
  sq += __shfl_xor(sq,16); sq += __shfl_xor(sq,32);
  if (cg==0) { stS[col]=ss; stQ[col]=sq; }
  __syncthreads();
  if (t < 40)
    statout[(size_t)blockIdx.x*40 + t] = make_float4(stS[2*t], stQ[2*t], stS[2*t+1], stQ[2*t+1]);
}

// ---------------- final: vf = elu(bn1(v2)+bn2(v1)+bn3(v0)) ----------------
__global__ __launch_bounds__(256) void k_final(
    const float* __restrict__ v2, const float* __restrict__ v1, const float* __restrict__ v0,
    const float4* __restrict__ s2, const float4* __restrict__ s1, const float4* __restrict__ s0,
    const float* __restrict__ g1, const float* __restrict__ b1,
    const float* __restrict__ g2, const float* __restrict__ b2,
    const float* __restrict__ g3, const float* __restrict__ b3,
    float* __restrict__ vf, int ns)
{
  __shared__ float A[3][CC], D[3][CC];
  __shared__ float4 pf[2][3][40];
  int t = threadIdx.x;
  if (t < 240) {
    int p = t % 40, s = (t/40) % 3, h = t/120;
    const float4* sp = s==0 ? s2 : (s==1 ? s1 : s0);
    int half = ns >> 1;
    const float4* base = sp + (size_t)(h*half)*40 + p;
    float4 acc = {0.f,0.f,0.f,0.f};
    int i=0;
    for (; i+8<=half; i+=8) {
      float4 v[8];
      #pragma unroll
      for (int j=0;j<8;++j) v[j] = base[(size_t)(i+j)*40];
      #pragma unroll
      for (int j=0;j<8;++j){ acc.x+=v[j].x; acc.y+=v[j].y; acc.z+=v[j].z; acc.w+=v[j].w; }
    }
    for (; i<half; ++i){
      float4 v = base[(size_t)i*40];
      acc.x+=v.x; acc.y+=v.y; acc.z+=v.z; acc.w+=v.w;
    }
    pf[h][s][p] = acc;
  }
  __syncthreads();
  if (t < 240) {
    int set = t/80, chl = t%80, p = chl>>1, e = chl&1;
    const float* gg  = set==0? g1 : (set==1? g2 : g3);
    const float* bbp = set==0? b1 : (set==1? b2 : b3);
    float4 a0 = pf[0][set][p], a1 = pf[1][set][p];
    float S = e ? (a0.z + a1.z) : (a0.x + a1.x);
    float Q = e ? (a0.w + a1.w) : (a0.y + a1.y);
    float mean = S*(1.f/ROWS_Y);
    float var  = fmaf(-mean,mean,Q*(1.f/ROWS_Y));
    float aa   = gg[chl]*rsqrtf(var+1e-5f);
    A[set][chl]=aa; D[set][chl]=bbp[chl]-mean*aa;
  }
  __syncthreads();
  for (size_t idx = (size_t)blockIdx.x*256 + t; idx < (size_t)ROWS_Y*CC; idx += (size_t)gridDim.x*256) {
    int c = (int)(idx % CC);
    float val = fmaf(v2[idx],A[0][c],D[0][c]) + fmaf(v1[idx],A[1][c],D[1][c]) + fmaf(v0[idx],A[2][c],D[2][c]);
    vf[idx] = val>0.f? val : expm1f(val);
  }
}

// ---------------- w[b,n] = sum_k mask[b,k] L[b,k,n] ----------------
__global__ __launch_bounds__(256) void k_w(
    const float* __restrict__ mask, const float* __restrict__ L, float* __restrict__ w)
{
  int bx = blockIdx.x;            // 32
  int b = bx >> 4, n0 = (bx & 15) * 64;
  int t = threadIdx.x;
  int ks = t >> 6;
  __shared__ float red[4][64];
  float acc=0.f;
  const float* Lb = L + (size_t)b*NN*NN;
  const float* mb = mask + b*NN;
  int n = n0 + (t & 63);
  for (int k = ks*256; k < ks*256+256; k+=8) {
    float mv[8], lv[8];
    #pragma unroll
    for (int j=0;j<8;++j){ mv[j]=mb[k+j]; lv[j]=Lb[(size_t)(k+j)*NN + n]; }
    #pragma unroll
    for (int j=0;j<8;++j) acc = fmaf(mv[j], lv[j], acc);
  }
  red[ks][t&63]=acc;
  __syncthreads();
  if (t < 64) w[b*NN + n0 + t] = red[0][t]+red[1][t]+red[2][t]+red[3][t];
}

// ---------------- pooled partials: p1 = sum mask*vf, p2 = sum w*vf ----------------
__global__ __launch_bounds__(256) void k_pool(
    const float* __restrict__ vf, const float* __restrict__ mask,
    const float* __restrict__ w, float* __restrict__ part)
{
  int bx = blockIdx.x;            // 16
  int b = bx >> 3, slab = bx & 7;
  int t = threadIdx.x, c = t%CC, rs = t/CC;
  __shared__ float st[3][2][CC];
  if (t<240) {
    float a1=0.f,a2=0.f;
    for (int r = rs; r < 128; r += 3) {
      int row = slab*128 + r;
      float val = vf[((size_t)b*NN + row)*CC + c];
      a1 = fmaf(mask[b*NN+row], val, a1);
      a2 = fmaf(w[b*NN+row],    val, a2);
    }
    st[rs][0][c]=a1; st[rs][1][c]=a2;
  }
  __syncthreads();
  if (t<CC) {
    part[((b*8+slab)*2+0)*CC+t] = st[0][0][t]+st[1][0][t]+st[2][0][t];
    part[((b*8+slab)*2+1)*CC+t] = st[0][1][t]+st[1][1][t]+st[2][1][t];
  }
}

// ---------------- out[b,co] = (p1@W0 + p2@W1)/msum + b2 ----------------
__global__ __launch_bounds__(256) void k_out(
    const float* __restrict__ part, const float* __restrict__ mask,
    const float* __restrict__ W0, const float* __restrict__ W1,
    const float* __restrict__ b2, float* __restrict__ outp)
{
  __shared__ float pl[2][2][CC];
  __shared__ float msred[2][128];
  __shared__ float ms[2];
  int t = threadIdx.x;
  {
    int b = t >> 7, k0 = t & 127;
    float m[8];
    #pragma unroll
    for (int j=0;j<8;++j) m[j] = mask[b*NN + k0 + j*128];
    msred[b][k0] = ((m[0]+m[1])+(m[2]+m[3]))+((m[4]+m[5])+(m[6]+m[7]));
  }
  if (t < 160) {
    int b = t/CC, c = t%CC;
    float v1[8], v2[8];
    #pragma unroll
    for (int slab=0; slab<8; ++slab){
      v1[slab] = part[((b*8+slab)*2+0)*CC+c];
      v2[slab] = part[((b*8+slab)*2+1)*CC+c];
    }
    float s1=0.f,s2=0.f;
    #pragma unroll
    for (int slab=0;slab<8;++slab){ s1+=v1[slab]; s2+=v2[slab]; }
    pl[b][0][c]=s1; pl[b][1][c]=s2;
  }
  __syncthreads();
  if (t < 2) {
    float s=0.f;
    for (int k=0;k<128;++k) s += msred[t][k];
    ms[t]=s;
  }
  __syncthreads();
  int b = t >> 7, co = t & 127;
  float acc = 0.f;
  for (int c=0;c<CC;c+=8) {
    float w0[8], w1[8];
    #pragma unroll
    for (int j=0;j<8;++j){ w0[j]=W0[(c+j)*128+co]; w1[j]=W1[(c+j)*128+co]; }
    #pragma unroll
    for (int j=0;j<8;++j) acc += pl[b][0][c+j]*w0[j] + pl[b][1][c+j]*w1[j];
  }
  outp[t] = acc/ms[b] + b2[co];
}

extern "C" void kernel_launch(void* const* d_in, const int* in_sizes, int n_in,
                              void* d_out, int out_size, void* d_ws, size_t ws_size,
                              hipStream_t stream)
{
  const float* inp  = (const float*)d_in[0];
  const float* L    = (const float*)d_in[1];
  const float* Di   = (const float*)d_in[2];
  const float* DiA  = (const float*)d_in[3];
  const float* mask = (const float*)d_in[4];
  const float* c1W0 = (const float*)d_in[5];
  const float* c1W1 = (const float*)d_in[6];
  const float* c1b  = (const float*)d_in[7];
  const float* bn0g = (const float*)d_in[8];
  const float* bn0b = (const float*)d_in[9];
  const float* fc0W = (const float*)d_in[10];
  const float* fc0b = (const float*)d_in[11];
  const float* bn1g = (const float*)d_in[12];
  const float* bn1b = (const float*)d_in[13];
  const float* fc1W = (const float*)d_in[14];
  const float* fc1b = (const float*)d_in[15];
  const float* fbn1g= (const float*)d_in[16];
  const float* fbn1b= (const float*)d_in[17];
  const float* fbn2g= (const float*)d_in[18];
  const float* fbn2b= (const float*)d_in[19];
  const float* fbn3g= (const float*)d_in[20];
  const float* fbn3b= (const float*)d_in[21];
  const float* c2W0 = (const float*)d_in[22];
  const float* c2W1 = (const float*)d_in[23];
  const float* c2b  = (const float*)d_in[24];

  float* ws = (float*)d_ws;
  size_t off = 0;
  auto alloc = [&](size_t n)->float* { float* p = ws + off; off += (n + 63) & ~(size_t)63; return p; };
  const size_t STFL = (size_t)1024*40*4;   // stat buffer: up to 1024 slots x 40 float4
  float* vb[3];   for (int i=0;i<3;++i) vb[i]   = alloc((size_t)BB*NN*CC);
  float* fb[2];   for (int i=0;i<2;++i) fb[i]   = alloc((size_t)BB*FF*CC);
  float* Dv       = alloc((size_t)BB*FF*CC);
  float* Df       = alloc((size_t)BB*NN*CC);
  float4* vstat[3];for (int i=0;i<3;++i) vstat[i]= (float4*)alloc(STFL);
  float4* fstat[2];for (int i=0;i<2;++i) fstat[i]= (float4*)alloc(STFL);
  float4* dvstat  = (float4*)alloc(STFL);
  float4* dfstat  = (float4*)alloc(STFL);
  float* vf       = alloc((size_t)BB*NN*CC);
  float* wv       = alloc((size_t)BB*NN);
  float* part     = alloc((size_t)16*2*CC);
  const size_t nDi = (size_t)BB*(4*FF)*(4*NN);      // 67,108,864 elems each
  _Float16* Dih  = (_Float16*)alloc(nDi/2);
  _Float16* DiAh = (_Float16*)alloc(nDi/2);
  bool usebf = (off*sizeof(float) <= ws_size);

  hipMemsetAsync(fb[0],    0, (size_t)BB*FF*CC*4, stream);
  hipMemsetAsync(fb[1],    0, (size_t)BB*FF*CC*4, stream);
  hipMemsetAsync(vb[1],    0, (size_t)BB*NN*CC*4, stream);
  hipMemsetAsync(fstat[0], 0, (size_t)256*40*16, stream);

  k_conv1<<<128,256,0,stream>>>(inp, L, c1W0, c1W1, c1b, vb[0], vstat[0]);

  int nsDv = usebf ? 512 : 1024;   // Di-dirac slots (grid 256 x 2)
  int nsDf = usebf ? 256 : 512;    // DiA-dirac slots (grid 128 x 2)
  int cur=0, p1=1, p2=2, fcur=0, fs=0;
  for (int it=0; it<NB_; ++it) {
    if (usebf) {
      if (it==0) k_dirac_mfma<true ><<<dim3(256,2),256,0,stream>>>(Di,  Dih, vb[cur], Dv, dvstat, 4*FF, 4*NN);
      else       k_dirac_mfma<false><<<dim3(256,2),256,0,stream>>>(Dih, Dih, vb[cur], Dv, dvstat, 4*FF, 4*NN);
    } else {
      k_dirac_f32<<<dim3(512,2),256,0,stream>>>(Di, vb[cur], Dv, dvstat, 4*FF, 4*NN);
    }
    k_fc<<<ROWS_X/16,320,0,stream>>>(fb[fcur], Dv, fstat[fs],256, dvstat,nsDv,
        bn0g+(size_t)it*C2, bn0b+(size_t)it*C2, fc0W+(size_t)it*C2*CC, fc0b+(size_t)it*CC,
        fb[1-fcur], fb[1-fcur], fstat[1-fs], ROWS_X, 1.f/ROWS_X);
    fcur = 1-fcur; fs = 1-fs;
    if (usebf) {
      if (it==0) k_dirac_mfma<true ><<<dim3(128,2),256,0,stream>>>(DiA,  DiAh, fb[fcur], Df, dfstat, 4*NN, 4*FF);
      else       k_dirac_mfma<false><<<dim3(128,2),256,0,stream>>>(DiAh, DiAh, fb[fcur], Df, dfstat, 4*NN, 4*FF);
    } else {
      k_dirac_f32<<<dim3(256,2),256,0,stream>>>(DiA, fb[fcur], Df, dfstat, 4*NN, 4*FF);
    }
    k_fc<<<ROWS_Y/16,320,0,stream>>>(vb[cur], Df, vstat[cur],128, dfstat,nsDf,
        bn1g+(size_t)it*C2, bn1b+(size_t)it*C2, fc1W+(size_t)it*C2*CC, fc1b+(size_t)it*CC,
        vb[p1], vb[p2], vstat[p2], ROWS_Y, 1.f/ROWS_Y);
    int tmp=p2; p2=p1; p1=cur; cur=tmp;
  }

  k_final<<<128,256,0,stream>>>(vb[cur],vb[p1],vb[p2], vstat[cur],vstat[p1],vstat[p2],
      fbn1g,fbn1b,fbn2g,fbn2b,fbn3g,fbn3b, vf, 128);
  k_w<<<32,256,0,stream>>>(mask, L, wv);
  k_pool<<<16,256,0,stream>>>(vf, mask, wv, part);
  k_out<<<1,256,0,stream>>>(part, mask, c2W0, c2W1, c2b, (float*)d_out);
}

// Round 19
// 1729.252 us; speedup vs baseline: 1.1581x; 1.1581x over previous
//
#include <hip/hip_runtime.h>
#include <cstdint>

#define BB 2
#define NN 1024
#define FF 2048
#define CC 80
#define C2 160
#define NB_ 15
#define ROWS_X (BB*FF)   /* 4096 */
#define ROWS_Y (BB*NN)   /* 2048 */
#define WTP 168          /* padded LDS row stride (fp16 elems) */

typedef __attribute__((ext_vector_type(8))) _Float16 half8;
typedef __attribute__((ext_vector_type(4))) _Float16 half4;
typedef __attribute__((ext_vector_type(4))) float f32x4;

// Soft barrier: sync waves + drain own LDS writes; no vmcnt drain.
__device__ __forceinline__ void softbar() {
  __builtin_amdgcn_sched_barrier(0);
  asm volatile("s_waitcnt lgkmcnt(0)" ::: "memory");
  __builtin_amdgcn_s_barrier();
  __builtin_amdgcn_sched_barrier(0);
}

// ---------------- conv1: v = in@W0 + (L@in)@W1 + b, + v-stats + fp16 xT copy ----------
__global__ __launch_bounds__(256) void k_conv1(
    const float* __restrict__ inp, const float* __restrict__ L,
    const float* __restrict__ W0, const float* __restrict__ W1,
    const float* __restrict__ bias, float* __restrict__ v,
    float4* __restrict__ vstat, _Float16* __restrict__ vT)
{
  int bx = blockIdx.x;            // 128 = 2 batches x 64 row-blocks
  int b = bx >> 6, rb = bx & 63;
  int row0 = rb * 16;
  __shared__ float red[256][3];
  __shared__ float lx[16][3];
  __shared__ float st[16][2][CC];
  int t = threadIdx.x;
  int rloc = t >> 4, sl = t & 15;
  const float* Lrow = L + ((size_t)b*NN + row0 + rloc) * NN;
  const float* ipb  = inp + (size_t)b*NN*3;
  float a0=0.f,a1=0.f,a2=0.f;
  for (int m = sl; m < NN; m += 16) {
    float lv = Lrow[m];
    a0 = fmaf(lv, ipb[m*3+0], a0);
    a1 = fmaf(lv, ipb[m*3+1], a1);
    a2 = fmaf(lv, ipb[m*3+2], a2);
  }
  red[t][0]=a0; red[t][1]=a1; red[t][2]=a2;
  __syncthreads();
  if (t < 48) {
    int row = t/3, ci = t%3;
    float s=0.f;
    for (int s2=0; s2<16; ++s2) s += red[row*16+s2][ci];
    lx[row][ci]=s;
  }
  __syncthreads();
  for (int o = t; o < 16*CC; o += 256) {
    int row = o/CC, c = o%CC;
    const float* ir = inp + ((size_t)b*NN + row0 + row)*3;
    float val = bias[c];
    #pragma unroll
    for (int ci=0; ci<3; ++ci)
      val += ir[ci]*W0[ci*CC+c] + lx[row][ci]*W1[ci*CC+c];
    v[((size_t)b*NN + row0 + row)*CC + c] = val;
    vT[((size_t)b*32 + c%20)*(4*NN) + (row0+row)*4 + c/20] = (_Float16)val;
    st[row][0][c] = val;
    st[row][1][c] = val*val;
  }
  __syncthreads();
  if (t < 40) {
    float s0=0.f,q0=0.f,s1=0.f,q1=0.f;
    for (int row=0; row<16; ++row){
      s0+=st[row][0][2*t];   q0+=st[row][1][2*t];
      s1+=st[row][0][2*t+1]; q1+=st[row][1][2*t+1];
    }
    vstat[(size_t)bx*40 + t] = make_float4(s0,q0,s1,q1);
  }
}

// ---------------- MFMA Dirac (r17 structure, fp16 xT staging): y = A@x + stats ----------
// x staged from PERSISTENT global fp16 xT[b][32][K] (written by producers):
// 5 half8 loads + 5 ds_write_b128 per thread per chunk (r17 did 10 float4
// loads + 40 cvt + 40 scalar ds_write_b16). MFMA/A-path/barriers identical.
// CVT=true (it=0): A read f32, cvt in-register, fp16 copy stored to Aout.
template<bool CVT>
__global__ __launch_bounds__(256) __attribute__((amdgpu_waves_per_eu(2,2)))
void k_dirac_mfma(
    const void* __restrict__ Ain, _Float16* __restrict__ Aout,
    const _Float16* __restrict__ xTg,
    float* __restrict__ y, float4* __restrict__ stat, int M, int K)
{
  int b = blockIdx.y;
  y += (size_t)b*(size_t)M*20;
  const _Float16* Ah = (const _Float16*)Ain + (size_t)b*M*K;
  const float*    Af = (const float*)Ain    + (size_t)b*M*K;
  _Float16* Ao = CVT ? (Aout + (size_t)b*M*K) : nullptr;
  const _Float16* xTb = xTg + (size_t)b*32*K;
  __shared__ _Float16 xT[2][2][32][264];
  __shared__ float cb_[2][8][64];
  __shared__ float stS[2][CC], stQ[2][CC];
  int t = threadIdx.x, lane = t & 63, w = t >> 6;
  int rw = w & 1, kh = w >> 1;
  int row0 = blockIdx.x*32 + rw*16;
  int cl = lane & 15, cg = lane >> 4;
  int KH = K >> 1;
  f32x4 acc0 = {0.f,0.f,0.f,0.f}, acc1 = {0.f,0.f,0.f,0.f};
  int nchunk = KH >> 8;
  size_t aoff = (size_t)(row0 + cl)*K + (size_t)kh*KH + cg*8;
  // staging map: i = t + j*256 in [0,1280): h2=i/640, q=(i%640)>>5, k8=(i%640)&31
  int i0 = t;
  int h2_[5], q_[5], k8_[5];
  #pragma unroll
  for (int j=0;j<5;++j) {
    int i = i0 + j*256;
    h2_[j] = i/640; int rem = i - h2_[j]*640;
    q_[j] = rem >> 5; k8_[j] = rem & 31;
  }

  // zero rows 20..31 of both buffers & halves (never staged; b1 garbage cols discarded)
  for (int i = t; i < 2*2*12*264; i += 256) {
    int bb = i / (2*12*264);
    int rem = i - bb*(2*12*264);
    int hh = rem / (12*264);
    int r2 = rem - hh*(12*264);
    xT[bb][hh][20 + r2/264][r2 % 264] = (_Float16)0.f;
  }
  { // stage chunk 0, both halves
    half8 s[5];
    #pragma unroll
    for (int j=0;j<5;++j)
      s[j] = *(const half8*)(xTb + (size_t)q_[j]*K + (size_t)h2_[j]*KH + k8_[j]*8);
    #pragma unroll
    for (int j=0;j<5;++j)
      *(half8*)(&xT[0][h2_[j]][q_[j]][k8_[j]*8]) = s[j];
  }
  half8 a_cur[8];
  if constexpr (!CVT) {
    #pragma unroll
    for (int ks=0;ks<8;++ks) a_cur[ks] = *(const half8*)(Ah + aoff + ks*32);
  }
  __syncthreads();

  for (int c=0; c<nchunk; ++c) {
    int cur = c & 1;
    bool more = (c+1 < nchunk);
    half8 s[5];
    half8 a_nxt[8];
    if (more) {                            // issue next-chunk x loads early
      #pragma unroll
      for (int j=0;j<5;++j)
        s[j] = *(const half8*)(xTb + (size_t)q_[j]*K + (size_t)h2_[j]*KH
                               + (size_t)(c+1)*256 + k8_[j]*8);
      if constexpr (!CVT) {
        const _Float16* An = Ah + aoff + (size_t)(c+1)*256;
        #pragma unroll
        for (int ks=0;ks<8;++ks) a_nxt[ks] = *(const half8*)(An + ks*32);
      }
    }
    if constexpr (CVT) {                   // load f32 A this chunk, cvt, store
      size_t ao = aoff + (size_t)c*256;
      #pragma unroll
      for (int ks=0;ks<8;++ks) {
        float4 f0 = *(const float4*)(Af + ao + ks*32);
        float4 f1 = *(const float4*)(Af + ao + ks*32 + 4);
        half8 a;
        a[0]=(_Float16)f0.x; a[1]=(_Float16)f0.y; a[2]=(_Float16)f0.z; a[3]=(_Float16)f0.w;
        a[4]=(_Float16)f1.x; a[5]=(_Float16)f1.y; a[6]=(_Float16)f1.z; a[7]=(_Float16)f1.w;
        a_cur[ks] = a;
        *(half8*)(Ao + ao + ks*32) = a;
      }
    }
    #pragma unroll
    for (int ks=0;ks<8;++ks) {
      half8 b0 = *(const half8*)(&xT[cur][kh][cl     ][ks*32 + cg*8]);
      half8 b1 = *(const half8*)(&xT[cur][kh][16 + cl][ks*32 + cg*8]);
      acc0 = __builtin_amdgcn_mfma_f32_16x16x32_f16(a_cur[ks], b0, acc0, 0,0,0);
      acc1 = __builtin_amdgcn_mfma_f32_16x16x32_f16(a_cur[ks], b1, acc1, 0,0,0);
    }
    if (more) {                            // publish next buffer, rotate A
      #pragma unroll
      for (int j=0;j<5;++j)
        *(half8*)(&xT[cur^1][h2_[j]][q_[j]][k8_[j]*8]) = s[j];
      if constexpr (!CVT) {
        #pragma unroll
        for (int ks=0;ks<8;++ks) a_cur[ks] = a_nxt[ks];
      }
    }
    softbar();                             // sync waves WITHOUT vmcnt drain
  }

  // combine k-halves: waves kh=1 publish, kh=0 accumulate
  if (kh == 1) {
    #pragma unroll
    for (int j=0;j<4;++j){ cb_[rw][j][lane]=acc0[j]; cb_[rw][4+j][lane]=acc1[j]; }
  }
  __syncthreads();
  if (kh == 0) {
    #pragma unroll
    for (int j=0;j<4;++j){ acc0[j]+=cb_[rw][j][lane]; acc1[j]+=cb_[rw][4+j][lane]; }
    #pragma unroll
    for (int j=0;j<4;++j) {
      float v = acc0[j];
      y[(size_t)(row0 + 4*cg + j)*20 + cl] = v;
      float s = v, sq = v*v;
      s  += __shfl_xor(s,16);  s  += __shfl_xor(s,32);
      sq += __shfl_xor(sq,16); sq += __shfl_xor(sq,32);
      if (cg==0) { stS[rw][j*20+cl]=s; stQ[rw][j*20+cl]=sq; }
    }
    #pragma unroll
    for (int j=0;j<4;++j) {
      float v = acc1[j];                   // cols>=4 discarded (garbage rows)
      if (cl < 4) y[(size_t)(row0 + 4*cg + j)*20 + 16 + cl] = v;
      float s = (cl<4)? v : 0.f, sq = (cl<4)? v*v : 0.f;
      s  += __shfl_xor(s,16);  s  += __shfl_xor(s,32);
      sq += __shfl_xor(sq,16); sq += __shfl_xor(sq,32);
      if (cg==0 && cl<4) { stS[rw][j*20+16+cl]=s; stQ[rw][j*20+16+cl]=sq; }
    }
  }
  __syncthreads();
  int slot = blockIdx.y*gridDim.x + blockIdx.x;
  if (t < 40) {
    float4 o;
    o.x = stS[0][2*t]  +stS[1][2*t];
    o.y = stQ[0][2*t]  +stQ[1][2*t];
    o.z = stS[0][2*t+1]+stS[1][2*t+1];
    o.w = stQ[0][2*t+1]+stQ[1][2*t+1];
    stat[(size_t)slot*40 + t] = o;
  }
}

// ---------------- f32 FMA Dirac fallback (ws too small) ----------------
__global__ __launch_bounds__(256) __attribute__((amdgpu_waves_per_eu(2,2)))
void k_dirac_f32(
    const float* __restrict__ A, const float* __restrict__ x,
    float* __restrict__ y, float4* __restrict__ stat, int M, int K)
{
  const int DR = 4;
  int b = blockIdx.y;
  A += (size_t)b*M*K; x += (size_t)b*(size_t)K*20; y += (size_t)b*(size_t)M*20;
  __shared__ float xs[2][20][256];
  __shared__ float stS[4][CC], stQ[4][CC];
  int t = threadIdx.x, lane = t & 63, w = t >> 6;
  int row0 = blockIdx.x*(4*DR) + w*DR;
  float acc[DR][20];
  #pragma unroll
  for (int r=0;r<DR;++r)
    #pragma unroll
    for (int q=0;q<20;++q) acc[r][q]=0.f;
  const float4* xv = (const float4*)x;
  int nchunk = K >> 8;
  const float* Abase = A + (size_t)row0*K + (lane<<2);
  {
    float4 s0[5];
    #pragma unroll
    for (int i=0;i<5;++i) s0[i] = xv[(size_t)t*5 + i];
    #pragma unroll
    for (int i=0;i<5;++i) {
      xs[0][4*i+0][t]=s0[i].x; xs[0][4*i+1][t]=s0[i].y;
      xs[0][4*i+2][t]=s0[i].z; xs[0][4*i+3][t]=s0[i].w;
    }
  }
  float4 a[DR];
  #pragma unroll
  for (int r=0;r<DR;++r) a[r] = *(const float4*)(Abase + (size_t)r*K);
  __syncthreads();
  for (int c=0; c<nchunk; ++c) {
    int cur = c & 1;
    bool more = (c+1 < nchunk);
    float4 st[5];
    if (more) {
      size_t kb = (size_t)(c+1)*256 + t;
      #pragma unroll
      for (int i=0;i<5;++i) st[i] = xv[kb*5 + i];
    }
    float4 af[DR];
    #pragma unroll
    for (int r=0;r<DR;++r) af[r] = a[r];
    if (more) {
      const float* An = Abase + (size_t)(c+1)*256;
      #pragma unroll
      for (int r=0;r<DR;++r) a[r] = *(const float4*)(An + (size_t)r*K);
    }
    #pragma unroll
    for (int q=0;q<20;++q) {
      float4 xq = *(const float4*)(&xs[cur][q][lane<<2]);
      #pragma unroll
      for (int r=0;r<DR;++r) {
        acc[r][q] = fmaf(af[r].x, xq.x, acc[r][q]);
        acc[r][q] = fmaf(af[r].y, xq.y, acc[r][q]);
        acc[r][q] = fmaf(af[r].z, xq.z, acc[r][q]);
        acc[r][q] = fmaf(af[r].w, xq.w, acc[r][q]);
      }
    }
    if (more) {
      #pragma unroll
      for (int i=0;i<5;++i) {
        xs[cur^1][4*i+0][t]=st[i].x; xs[cur^1][4*i+1][t]=st[i].y;
        xs[cur^1][4*i+2][t]=st[i].z; xs[cur^1][4*i+3][t]=st[i].w;
      }
    }
    __syncthreads();
  }
  #pragma unroll
  for (int r=0;r<DR;++r) {
    #pragma unroll
    for (int q=0;q<20;++q) {
      float s = acc[r][q];
      s += __shfl_xor(s, 1);  s += __shfl_xor(s, 2);
      s += __shfl_xor(s, 4);  s += __shfl_xor(s, 8);
      s += __shfl_xor(s, 16); s += __shfl_xor(s, 32);
      acc[r][q]=s;
    }
    if (lane==0) {
      float4* yp = (float4*)(y + (size_t)(row0+r)*20);
      yp[0] = make_float4(acc[r][0],acc[r][1],acc[r][2],acc[r][3]);
      yp[1] = make_float4(acc[r][4],acc[r][5],acc[r][6],acc[r][7]);
      yp[2] = make_float4(acc[r][8],acc[r][9],acc[r][10],acc[r][11]);
      yp[3] = make_float4(acc[r][12],acc[r][13],acc[r][14],acc[r][15]);
      yp[4] = make_float4(acc[r][16],acc[r][17],acc[r][18],acc[r][19]);
    }
  }
  if (lane == 0) {
    #pragma unroll
    for (int r=0;r<DR;++r)
      #pragma unroll
      for (int q=0;q<20;++q) {
        float v0 = acc[r][q];
        stS[w][r*20+q] = v0;
        stQ[w][r*20+q] = v0*v0;
      }
  }
  __syncthreads();
  int slot = blockIdx.y*gridDim.x + blockIdx.x;
  if (t < 40) {
    float4 o;
    o.x = stS[0][2*t]+stS[1][2*t]+stS[2][2*t]+stS[3][2*t];
    o.y = stQ[0][2*t]+stQ[1][2*t]+stQ[2][2*t]+stQ[3][2*t];
    o.z = stS[0][2*t+1]+stS[1][2*t+1]+stS[2][2*t+1]+stS[3][2*t+1];
    o.w = stQ[0][2*t+1]+stQ[1][2*t+1]+stQ[2][2*t+1]+stQ[3][2*t+1];
    stat[(size_t)slot*40 + t] = o;
  }
}

// ---------------- MFMA fused BN(fold)+FC+ELU+residual + stats + coalesced fp16 xT ------
__global__ __launch_bounds__(320) void k_fc(
    const float* __restrict__ p1, const float* __restrict__ p2,
    const float4* __restrict__ sp1, int ns1,
    const float4* __restrict__ sp2, int ns2,
    const float* __restrict__ g, const float* __restrict__ bb,
    const float* __restrict__ W, const float* __restrict__ cb,
    const float* add, float* out,
    float4* __restrict__ statout, int rows, float invrows,
    _Float16* __restrict__ xTout, int rpbs)
{
  __shared__ _Float16 Wt[80*WTP];
  __shared__ _Float16 xh[16*WTP];
  __shared__ _Float16 xtt[20][68];
  __shared__ float ad[2][C2];
  __shared__ float bpl[CC];
  __shared__ float4 pst[2][2][40];
  __shared__ float stS[CC], stQ[CC];
  int t = threadIdx.x;
  int lane = t & 63, wv = t >> 6;          // wv = col-tile 0..4
  int cl = lane & 15, cg = lane >> 4;
  int r0 = blockIdx.x * 16;

  // phase 0: stats reduce (t<160)  ||  W transpose+fp16 convert (t>=160)
  if (t < 160) {
    int p = t % 40, s = (t/40) & 1, h = t/80;
    const float4* sp = s ? sp2 : sp1;
    int ns = s ? ns2 : ns1;
    int half = ns >> 1;
    const float4* base = sp + (size_t)(h*half)*40 + p;
    float4 acc = {0.f,0.f,0.f,0.f};
    int i=0;
    for (; i+8<=half; i+=8) {
      float4 v[8];
      #pragma unroll
      for (int j=0;j<8;++j) v[j] = base[(size_t)(i+j)*40];
      #pragma unroll
      for (int j=0;j<8;++j){ acc.x+=v[j].x; acc.y+=v[j].y; acc.z+=v[j].z; acc.w+=v[j].w; }
    }
    for (; i<half; ++i){
      float4 v = base[(size_t)i*40];
      acc.x+=v.x; acc.y+=v.y; acc.z+=v.z; acc.w+=v.w;
    }
    pst[h][s][p] = acc;
  } else {
    int t2 = t - 160;                      // 0..159; 20 float4 each = 3200 total
    #pragma unroll
    for (int i=0;i<20;++i) {
      int f4 = t2 + i*160;
      float4 w4 = ((const float4*)W)[f4];
      int c2 = f4/20, c = (f4%20)*4;
      Wt[(c+0)*WTP + c2] = (_Float16)w4.x;
      Wt[(c+1)*WTP + c2] = (_Float16)w4.y;
      Wt[(c+2)*WTP + c2] = (_Float16)w4.z;
      Wt[(c+3)*WTP + c2] = (_Float16)w4.w;
    }
  }
  __syncthreads();

  // phase 1: BN fold coeffs (t<160)  ||  all threads: B-frags from Wt -> regs
  half8 bfr[5];
  #pragma unroll
  for (int ks=0;ks<5;++ks)
    bfr[ks] = *(const half8*)(&Wt[(wv*16+cl)*WTP + ks*32 + cg*8]);
  if (t < C2) {
    int s = (t < CC) ? 0 : 1;
    int chl = (t < CC) ? t : t - CC;
    int p = chl >> 1, e = chl & 1;
    float4 a0 = pst[0][s][p], a1 = pst[1][s][p];
    float S = e ? (a0.z + a1.z) : (a0.x + a1.x);
    float Q = e ? (a0.w + a1.w) : (a0.y + a1.y);
    float mean = S*invrows;
    float var  = fmaf(-mean, mean, Q*invrows);
    float aa   = g[t]*rsqrtf(var + 1e-5f);
    ad[0][t]=aa; ad[1][t]= bb[t] - mean*aa;
  }
  __syncthreads();

  // phase 2: stage x-hat (16 rows, scaled by ad0, fp16)  ||  t<80: bpl
  #pragma unroll
  for (int i=0;i<2;++i) {
    int f4 = t + i*320;                    // 0..639
    if (f4 < 640) {
      int row = f4/40, cq = (f4%40)*4;     // cq in 0..156, never crosses 80
      const float* src = (cq < 80) ? (p1 + (size_t)(r0+row)*CC + cq)
                                   : (p2 + (size_t)(r0+row)*CC + cq - 80);
      float4 x4 = *(const float4*)src;
      half4 h4;
      h4[0]=(_Float16)(x4.x*ad[0][cq+0]); h4[1]=(_Float16)(x4.y*ad[0][cq+1]);
      h4[2]=(_Float16)(x4.z*ad[0][cq+2]); h4[3]=(_Float16)(x4.w*ad[0][cq+3]);
      *(half4*)(&xh[row*WTP + cq]) = h4;
    }
  }
  if (t < CC) {
    float s = cb[t];
    #pragma unroll
    for (int ks=0;ks<20;++ks) {
      half8 w8 = *(const half8*)(&Wt[t*WTP + ks*8]);
      #pragma unroll
      for (int j=0;j<8;++j) s = fmaf(ad[1][ks*8+j], (float)w8[j], s);
    }
    bpl[t]=s;
  }
  __syncthreads();

  // phase 3: A-frags, 5 MFMA, epilogue (+ fp16 xT tile via LDS, coalesced store)
  half8 afr[5];
  #pragma unroll
  for (int ks=0;ks<5;++ks)
    afr[ks] = *(const half8*)(&xh[cl*WTP + ks*32 + cg*8]);
  f32x4 acc = {0.f,0.f,0.f,0.f};
  #pragma unroll
  for (int ks=0;ks<5;++ks)
    acc = __builtin_amdgcn_mfma_f32_16x16x32_f16(afr[ks], bfr[ks], acc, 0,0,0);
  float ss=0.f, sq=0.f;
  int col = wv*16 + cl;
  int q20 = col % 20, c4 = col / 20;
  #pragma unroll
  for (int j=0;j<4;++j) {
    int row = r0 + 4*cg + j;
    float val = acc[j] + bpl[col];
    val = val>0.f ? val : expm1f(val);
    val += add[(size_t)row*CC + col];
    out[(size_t)row*CC + col] = val;
    xtt[q20][(4*cg+j)*4 + c4] = (_Float16)val;
    ss += val; sq = fmaf(val,val,sq);
  }
  ss += __shfl_xor(ss,16); ss += __shfl_xor(ss,32);
  sq += __shfl_xor(sq,16); sq += __shfl_xor(sq,32);
  if (cg==0) { stS[col]=ss; stQ[col]=sq; }
  __syncthreads();
  if (t < 160) {                           // coalesced xT store: 20 q x 64 k
    int q = t/8, k8 = t%8;
    size_t Kx = (size_t)4 << rpbs;
    int bb2 = r0 >> rpbs;
    int rl  = r0 & ((1<<rpbs)-1);
    half8 v = *(const half8*)(&xtt[q][k8*8]);
    *(half8*)(xTout + ((size_t)bb2*32 + q)*Kx + (size_t)rl*4 + k8*8) = v;
  }
  if (t < 40)
    statout[(size_t)blockIdx.x*40 + t] = make_float4(stS[2*t], stQ[2*t], stS[2*t+1], stQ[2*t+1]);
}

// ---------------- final: vf = elu(bn1(v2)+bn2(v1)+bn3(v0)) ----------------
__global__ __launch_bounds__(256) void k_final(
    const float* __restrict__ v2, const float* __restrict__ v1, const float* __restrict__ v0,
    const float4* __restrict__ s2, const float4* __restrict__ s1, const float4* __restrict__ s0,
    const float* __restrict__ g1, const float* __restrict__ b1,
    const float* __restrict__ g2, const float* __restrict__ b2,
    const float* __restrict__ g3, const float* __restrict__ b3,
    float* __restrict__ vf, int ns)
{
  __shared__ float A[3][CC], D[3][CC];
  __shared__ float4 pf[2][3][40];
  int t = threadIdx.x;
  if (t < 240) {
    int p = t % 40, s = (t/40) % 3, h = t/120;
    const float4* sp = s==0 ? s2 : (s==1 ? s1 : s0);
    int half = ns >> 1;
    const float4* base = sp + (size_t)(h*half)*40 + p;
    float4 acc = {0.f,0.f,0.f,0.f};
    int i=0;
    for (; i+8<=half; i+=8) {
      float4 v[8];
      #pragma unroll
      for (int j=0;j<8;++j) v[j] = base[(size_t)(i+j)*40];
      #pragma unroll
      for (int j=0;j<8;++j){ acc.x+=v[j].x; acc.y+=v[j].y; acc.z+=v[j].z; acc.w+=v[j].w; }
    }
    for (; i<half; ++i){
      float4 v = base[(size_t)i*40];
      acc.x+=v.x; acc.y+=v.y; acc.z+=v.z; acc.w+=v.w;
    }
    pf[h][s][p] = acc;
  }
  __syncthreads();
  if (t < 240) {
    int set = t/80, chl = t%80, p = chl>>1, e = chl&1;
    const float* gg  = set==0? g1 : (set==1? g2 : g3);
    const float* bbp = set==0? b1 : (set==1? b2 : b3);
    float4 a0 = pf[0][set][p], a1 = pf[1][set][p];
    float S = e ? (a0.z + a1.z) : (a0.x + a1.x);
    float Q = e ? (a0.w + a1.w) : (a0.y + a1.y);
    float mean = S*(1.f/ROWS_Y);
    float var  = fmaf(-mean,mean,Q*(1.f/ROWS_Y));
    float aa   = gg[chl]*rsqrtf(var+1e-5f);
    A[set][chl]=aa; D[set][chl]=bbp[chl]-mean*aa;
  }
  __syncthreads();
  for (size_t idx = (size_t)blockIdx.x*256 + t; idx < (size_t)ROWS_Y*CC; idx += (size_t)gridDim.x*256) {
    int c = (int)(idx % CC);
    float val = fmaf(v2[idx],A[0][c],D[0][c]) + fmaf(v1[idx],A[1][c],D[1][c]) + fmaf(v0[idx],A[2][c],D[2][c]);
    vf[idx] = val>0.f? val : expm1f(val);
  }
}

// ---------------- w[b,n] = sum_k mask[b,k] L[b,k,n] ----------------
__global__ __launch_bounds__(256) void k_w(
    const float* __restrict__ mask, const float* __restrict__ L, float* __restrict__ w)
{
  int bx = blockIdx.x;            // 32
  int b = bx >> 4, n0 = (bx & 15) * 64;
  int t = threadIdx.x;
  int ks = t >> 6;
  __shared__ float red[4][64];
  float acc=0.f;
  const float* Lb = L + (size_t)b*NN*NN;
  const float* mb = mask + b*NN;
  int n = n0 + (t & 63);
  for (int k = ks*256; k < ks*256+256; k+=8) {
    float mv[8], lv[8];
    #pragma unroll
    for (int j=0;j<8;++j){ mv[j]=mb[k+j]; lv[j]=Lb[(size_t)(k+j)*NN + n]; }
    #pragma unroll
    for (int j=0;j<8;++j) acc = fmaf(mv[j], lv[j], acc);
  }
  red[ks][t&63]=acc;
  __syncthreads();
  if (t < 64) w[b*NN + n0 + t] = red[0][t]+red[1][t]+red[2][t]+red[3][t];
}

// ---------------- pooled partials: p1 = sum mask*vf, p2 = sum w*vf ----------------
__global__ __launch_bounds__(256) void k_pool(
    const float* __restrict__ vf, const float* __restrict__ mask,
    const float* __restrict__ w, float* __restrict__ part)
{
  int bx = blockIdx.x;            // 16
  int b = bx >> 3, slab = bx & 7;
  int t = threadIdx.x, c = t%CC, rs = t/CC;
  __shared__ float st[3][2][CC];
  if (t<240) {
    float a1=0.f,a2=0.f;
    for (int r = rs; r < 128; r += 3) {
      int row = slab*128 + r;
      float val = vf[((size_t)b*NN + row)*CC + c];
      a1 = fmaf(mask[b*NN+row], val, a1);
      a2 = fmaf(w[b*NN+row],    val, a2);
    }
    st[rs][0][c]=a1; st[rs][1][c]=a2;
  }
  __syncthreads();
  if (t<CC) {
    part[((b*8+slab)*2+0)*CC+t] = st[0][0][t]+st[1][0][t]+st[2][0][t];
    part[((b*8+slab)*2+1)*CC+t] = st[0][1][t]+st[1][1][t]+st[2][1][t];
  }
}

// ---------------- out[b,co] = (p1@W0 + p2@W1)/msum + b2 ----------------
__global__ __launch_bounds__(256) void k_out(
    const float* __restrict__ part, const float* __restrict__ mask,
    const float* __restrict__ W0, const float* __restrict__ W1,
    const float* __restrict__ b2, float* __restrict__ outp)
{
  __shared__ float pl[2][2][CC];
  __shared__ float msred[2][128];
  __shared__ float ms[2];
  int t = threadIdx.x;
  {
    int b = t >> 7, k0 = t & 127;
    float m[8];
    #pragma unroll
    for (int j=0;j<8;++j) m[j] = mask[b*NN + k0 + j*128];
    msred[b][k0] = ((m[0]+m[1])+(m[2]+m[3]))+((m[4]+m[5])+(m[6]+m[7]));
  }
  if (t < 160) {
    int b = t/CC, c = t%CC;
    float v1[8], v2[8];
    #pragma unroll
    for (int slab=0; slab<8; ++slab){
      v1[slab] = part[((b*8+slab)*2+0)*CC+c];
      v2[slab] = part[((b*8+slab)*2+1)*CC+c];
    }
    float s1=0.f,s2=0.f;
    #pragma unroll
    for (int slab=0;slab<8;++slab){ s1+=v1[slab]; s2+=v2[slab]; }
    pl[b][0][c]=s1; pl[b][1][c]=s2;
  }
  __syncthreads();
  if (t < 2) {
    float s=0.f;
    for (int k=0;k<128;++k) s += msred[t][k];
    ms[t]=s;
  }
  __syncthreads();
  int b = t >> 7, co = t & 127;
  float acc = 0.f;
  for (int c=0;c<CC;c+=8) {
    float w0[8], w1[8];
    #pragma unroll
    for (int j=0;j<8;++j){ w0[j]=W0[(c+j)*128+co]; w1[j]=W1[(c+j)*128+co]; }
    #pragma unroll
    for (int j=0;j<8;++j) acc += pl[b][0][c+j]*w0[j] + pl[b][1][c+j]*w1[j];
  }
  outp[t] = acc/ms[b] + b2[co];
}

extern "C" void kernel_launch(void* const* d_in, const int* in_sizes, int n_in,
                              void* d_out, int out_size, void* d_ws, size_t ws_size,
                              hipStream_t stream)
{
  const float* inp  = (const float*)d_in[0];
  const float* L    = (const float*)d_in[1];
  const float* Di   = (const float*)d_in[2];
  const float* DiA  = (const float*)d_in[3];
  const float* mask = (const float*)d_in[4];
  const float* c1W0 = (const float*)d_in[5];
  const float* c1W1 = (const float*)d_in[6];
  const float* c1b  = (const float*)d_in[7];
  const float* bn0g = (const float*)d_in[8];
  const float* bn0b = (const float*)d_in[9];
  const float* fc0W = (const float*)d_in[10];
  const float* fc0b = (const float*)d_in[11];
  const float* bn1g = (const float*)d_in[12];
  const float* bn1b = (const float*)d_in[13];
  const float* fc1W = (const float*)d_in[14];
  const float* fc1b = (const float*)d_in[15];
  const float* fbn1g= (const float*)d_in[16];
  const float* fbn1b= (const float*)d_in[17];
  const float* fbn2g= (const float*)d_in[18];
  const float* fbn2b= (const float*)d_in[19];
  const float* fbn3g= (const float*)d_in[20];
  const float* fbn3b= (const float*)d_in[21];
  const float* c2W0 = (const float*)d_in[22];
  const float* c2W1 = (const float*)d_in[23];
  const float* c2b  = (const float*)d_in[24];

  float* ws = (float*)d_ws;
  size_t off = 0;
  auto alloc = [&](size_t n)->float* { float* p = ws + off; off += (n + 63) & ~(size_t)63; return p; };
  const size_t STFL = (size_t)1024*40*4;   // stat buffer: up to 1024 slots x 40 float4
  float* vb[3];   for (int i=0;i<3;++i) vb[i]   = alloc((size_t)BB*NN*CC);
  float* fb[2];   for (int i=0;i<2;++i) fb[i]   = alloc((size_t)BB*FF*CC);
  float* Dv       = alloc((size_t)BB*FF*CC);
  float* Df       = alloc((size_t)BB*NN*CC);
  float4* vstat[3];for (int i=0;i<3;++i) vstat[i]= (float4*)alloc(STFL);
  float4* fstat[2];for (int i=0;i<2;++i) fstat[i]= (float4*)alloc(STFL);
  float4* dvstat  = (float4*)alloc(STFL);
  float4* dfstat  = (float4*)alloc(STFL);
  float* vf       = alloc((size_t)BB*NN*CC);
  float* wv       = alloc((size_t)BB*NN);
  float* part     = alloc((size_t)16*2*CC);
  _Float16* xTv   = (_Float16*)alloc((size_t)BB*32*(4*NN)/2);   // [B][32][4096] fp16
  _Float16* xTf   = (_Float16*)alloc((size_t)BB*32*(4*FF)/2);   // [B][32][8192] fp16
  const size_t nDi = (size_t)BB*(4*FF)*(4*NN);      // 67,108,864 elems each
  _Float16* Dih  = (_Float16*)alloc(nDi/2);
  _Float16* DiAh = (_Float16*)alloc(nDi/2);
  bool usebf = (off*sizeof(float) <= ws_size);

  hipMemsetAsync(fb[0],    0, (size_t)BB*FF*CC*4, stream);
  hipMemsetAsync(fb[1],    0, (size_t)BB*FF*CC*4, stream);
  hipMemsetAsync(vb[1],    0, (size_t)BB*NN*CC*4, stream);
  hipMemsetAsync(fstat[0], 0, (size_t)256*40*16, stream);

  k_conv1<<<128,256,0,stream>>>(inp, L, c1W0, c1W1, c1b, vb[0], vstat[0], xTv);

  int nsDv = usebf ? 512 : 1024;   // Di-dirac slots (grid 256 x 2)
  int nsDf = usebf ? 256 : 512;    // DiA-dirac slots (grid 128 x 2)
  int cur=0, p1=1, p2=2, fcur=0, fs=0;
  for (int it=0; it<NB_; ++it) {
    if (usebf) {
      if (it==0) k_dirac_mfma<true ><<<dim3(256,2),256,0,stream>>>(Di,  Dih, xTv, Dv, dvstat, 4*FF, 4*NN);
      else       k_dirac_mfma<false><<<dim3(256,2),256,0,stream>>>(Dih, Dih, xTv, Dv, dvstat, 4*FF, 4*NN);
    } else {
      k_dirac_f32<<<dim3(512,2),256,0,stream>>>(Di, vb[cur], Dv, dvstat, 4*FF, 4*NN);
    }
    k_fc<<<ROWS_X/16,320,0,stream>>>(fb[fcur], Dv, fstat[fs],256, dvstat,nsDv,
        bn0g+(size_t)it*C2, bn0b+(size_t)it*C2, fc0W+(size_t)it*C2*CC, fc0b+(size_t)it*CC,
        fb[1-fcur], fb[1-fcur], fstat[1-fs], ROWS_X, 1.f/ROWS_X, xTf, 11);
    fcur = 1-fcur; fs = 1-fs;
    if (usebf) {
      if (it==0) k_dirac_mfma<true ><<<dim3(128,2),256,0,stream>>>(DiA,  DiAh, xTf, Df, dfstat, 4*NN, 4*FF);
      else       k_dirac_mfma<false><<<dim3(128,2),256,0,stream>>>(DiAh, DiAh, xTf, Df, dfstat, 4*NN, 4*FF);
    } else {
      k_dirac_f32<<<dim3(256,2),256,0,stream>>>(DiA, fb[fcur], Df, dfstat, 4*NN, 4*FF);
    }
    k_fc<<<ROWS_Y/16,320,0,stream>>>(vb[cur], Df, vstat[cur],128, dfstat,nsDf,
        bn1g+(size_t)it*C2, bn1b+(size_t)it*C2, fc1W+(size_t)it*C2*CC, fc1b+(size_t)it*CC,
        vb[p1], vb[p2], vstat[p2], ROWS_Y, 1.f/ROWS_Y, xTv, 10);
    int tmp=p2; p2=p1; p1=cur; cur=tmp;
  }

  k_final<<<128,256,0,stream>>>(vb[cur],vb[p1],vb[p2], vstat[cur],vstat[p1],vstat[p2],
      fbn1g,fbn1b,fbn2g,fbn2b,fbn3g,fbn3b, vf, 128);
  k_w<<<32,256,0,stream>>>(mask, L, wv);
  k_pool<<<16,256,0,stream>>>(vf, mask, wv, part);
  k_out<<<1,256,0,stream>>>(part, mask, c2W0, c2W1, c2b, (float*)d_out);
}